// Round 1
// baseline (230.395 us; speedup 1.0000x reference)
//
#include <hip/hip_runtime.h>

typedef __attribute__((ext_vector_type(8))) short short8;
typedef __attribute__((ext_vector_type(4))) float f32x4;
typedef __attribute__((ext_vector_type(4))) unsigned short ushort4v;
typedef unsigned short u16;

#define NN 1024
#define DD 512
#define DH 64
#define ATT_SCALE 0.125f

// ---------- helpers ----------

__device__ __forceinline__ u16 f2bf(float f) {
    unsigned u = __float_as_uint(f);
    u += 0x7fffu + ((u >> 16) & 1u);   // RNE
    return (u16)(u >> 16);
}

// swizzled LDS reads: physical = (row*LD + colbyte) ^ ((row&7)<<4)
__device__ __forceinline__ short8 lds_ld128(const char* base, int row, int colbyte) {
    int off = (row * 128 + colbyte) ^ ((row & 7) << 4);
    return *(const short8*)(base + off);
}
__device__ __forceinline__ short8 lds_ld256(const char* base, int row, int colbyte) {
    int off = (row * 256 + colbyte) ^ ((row & 7) << 4);
    return *(const short8*)(base + off);
}

// stage 128 rows x 64 cols bf16 (16KB) tile; global row-major, ldRow elements.
// LDS layout has the (row&7) XOR swizzle applied; we pre-swizzle the SOURCE
// address and keep the global_load_lds destination linear (m173 pattern).
__device__ __forceinline__ void stage128x64(const u16* g, int ldRow, char* lds,
                                            int wid, int lane) {
#pragma unroll
    for (int r = 0; r < 4; ++r) {
        int cidx = (r * 4 + wid) * 64 + lane;        // 16B chunk index, 1024 total
        int row  = cidx >> 3;                        // 8 chunks per 128B row
        int ch   = (cidx & 7) ^ (row & 7);           // inverse-swizzled source chunk
        const char* src = (const char*)(g + row * ldRow) + ch * 16;
        __builtin_amdgcn_global_load_lds(
            (const __attribute__((address_space(1))) unsigned int*)src,
            (__attribute__((address_space(3))) unsigned int*)(lds + (r * 4 + wid) * 1024),
            16, 0, 0);
    }
}

// stage 64 rows x 128 cols bf16 (16KB); LDS rows are 256B
__device__ __forceinline__ void stage64x128(const u16* g, int ldRow, char* lds,
                                            int wid, int lane) {
#pragma unroll
    for (int r = 0; r < 4; ++r) {
        int cidx = (r * 4 + wid) * 64 + lane;
        int row  = cidx >> 4;                        // 16 chunks per 256B row
        int ch   = (cidx & 15) ^ (row & 7);
        const char* src = (const char*)(g + row * ldRow) + ch * 16;
        __builtin_amdgcn_global_load_lds(
            (const __attribute__((address_space(1))) unsigned int*)src,
            (__attribute__((address_space(3))) unsigned int*)(lds + (r * 4 + wid) * 1024),
            16, 0, 0);
    }
}

// ---------- fp32 -> bf16 convert ----------

__global__ void f2bf_k(const float* __restrict__ in, u16* __restrict__ out, int n4) {
    int i = blockIdx.x * blockDim.x + threadIdx.x;
    if (i < n4) {
        float4 v = ((const float4*)in)[i];
        ushort4v o;
        o.x = f2bf(v.x); o.y = f2bf(v.y); o.z = f2bf(v.z); o.w = f2bf(v.w);
        *(ushort4v*)(out + (size_t)i * 4) = o;
    }
}

// ---------- GEMM: C[M,512] = A[M,512] @ B[512,512]^T ----------
// MODE 0: bf16 row-major out   MODE 1: bf16 transposed out [512][8192]
// MODE 2: fp32 out + bias
template <int MODE>
__global__ __launch_bounds__(256, 2) void gemm_bt(
    const u16* __restrict__ A, const u16* __restrict__ B,
    void* __restrict__ Out, const float* __restrict__ bias)
{
    __shared__ char As[16384];
    __shared__ char Bs[16384];
    const int lane = threadIdx.x & 63;
    const int wid  = threadIdx.x >> 6;
    const int wr = wid >> 1, wc = wid & 1;
    const int rowBase = blockIdx.y * 128;
    const int colBase = blockIdx.x * 128;

    f32x4 acc[4][4] = {};
    for (int kt = 0; kt < 8; ++kt) {
        __syncthreads();
        stage128x64(A + (size_t)rowBase * DD + kt * 64, DD, As, wid, lane);
        stage128x64(B + (size_t)colBase * DD + kt * 64, DD, Bs, wid, lane);
        __syncthreads();
#pragma unroll
        for (int kk = 0; kk < 2; ++kk) {
            const int cb = kk * 64 + (lane >> 4) * 16;
            short8 af[4], bf[4];
#pragma unroll
            for (int m = 0; m < 4; ++m) af[m] = lds_ld128(As, wr * 64 + m * 16 + (lane & 15), cb);
#pragma unroll
            for (int n = 0; n < 4; ++n) bf[n] = lds_ld128(Bs, wc * 64 + n * 16 + (lane & 15), cb);
#pragma unroll
            for (int m = 0; m < 4; ++m) {
#pragma unroll
                for (int n = 0; n < 4; ++n)
                    acc[m][n] = __builtin_amdgcn_mfma_f32_16x16x32_bf16(af[m], bf[n], acc[m][n], 0, 0, 0);
            }
        }
    }
#pragma unroll
    for (int m = 0; m < 4; ++m) {
#pragma unroll
        for (int n = 0; n < 4; ++n) {
            const int r0 = rowBase + wr * 64 + m * 16 + ((lane >> 4) << 2);
            const int c  = colBase + wc * 64 + n * 16 + (lane & 15);
            if (MODE == 0) {
                u16* O = (u16*)Out;
#pragma unroll
                for (int g = 0; g < 4; ++g) O[(size_t)(r0 + g) * DD + c] = f2bf(acc[m][n][g]);
            } else if (MODE == 1) {
                u16* O = (u16*)Out;      // [512][8192]
                ushort4v pk;
#pragma unroll
                for (int g = 0; g < 4; ++g) pk[g] = f2bf(acc[m][n][g]);
                *(ushort4v*)(O + (size_t)c * 8192 + r0) = pk;
            } else {
                float* O = (float*)Out;
                const float bb = bias[c];
#pragma unroll
                for (int g = 0; g < 4; ++g) O[(size_t)(r0 + g) * DD + c] = acc[m][n][g] + bb;
            }
        }
    }
}

// ---------- pass 1: inv column-sum of exp(sim) ----------
// grid (8 jtiles, 64 bh); per block: 128 j-cols, loop all 1024 i
__global__ __launch_bounds__(256, 2) void colsum_k(
    const u16* __restrict__ qb, const u16* __restrict__ kb, float* __restrict__ invcol)
{
    __shared__ char Qs[16384];
    __shared__ float csum[128];
    const int lane = threadIdx.x & 63;
    const int wid  = threadIdx.x >> 6;
    const int wr = wid >> 1, wc = wid & 1;
    const int jt = blockIdx.x;
    const int bh = blockIdx.y;
    const int b = bh >> 3, h = bh & 7;
    if (threadIdx.x < 128) csum[threadIdx.x] = 0.0f;

    // K fragments (B operand) stay in registers for the whole block
    short8 kf[4][2];
#pragma unroll
    for (int n = 0; n < 4; ++n) {
#pragma unroll
        for (int kk = 0; kk < 2; ++kk) {
            const int j = jt * 128 + wc * 64 + n * 16 + (lane & 15);
            kf[n][kk] = *(const short8*)(kb + (size_t)(b * NN + j) * DD + h * DH + kk * 32 + ((lane >> 4) << 3));
        }
    }
    float colpart[4] = {0.f, 0.f, 0.f, 0.f};
    for (int it = 0; it < 8; ++it) {
        __syncthreads();
        stage128x64(qb + (size_t)(b * NN + it * 128) * DD + h * DH, DD, Qs, wid, lane);
        __syncthreads();
        f32x4 acc[4][4] = {};
#pragma unroll
        for (int kk = 0; kk < 2; ++kk) {
            const int cb = kk * 64 + (lane >> 4) * 16;
            short8 af[4];
#pragma unroll
            for (int m = 0; m < 4; ++m) af[m] = lds_ld128(Qs, wr * 64 + m * 16 + (lane & 15), cb);
#pragma unroll
            for (int m = 0; m < 4; ++m) {
#pragma unroll
                for (int n = 0; n < 4; ++n)
                    acc[m][n] = __builtin_amdgcn_mfma_f32_16x16x32_bf16(af[m], kf[n][kk], acc[m][n], 0, 0, 0);
            }
        }
#pragma unroll
        for (int n = 0; n < 4; ++n) {
#pragma unroll
            for (int m = 0; m < 4; ++m) {
#pragma unroll
                for (int g = 0; g < 4; ++g)
                    colpart[n] += __expf(acc[m][n][g] * ATT_SCALE);
            }
        }
    }
#pragma unroll
    for (int n = 0; n < 4; ++n) {
        colpart[n] += __shfl_xor(colpart[n], 16);
        colpart[n] += __shfl_xor(colpart[n], 32);
    }
    if ((lane >> 4) == 0) {
#pragma unroll
        for (int n = 0; n < 4; ++n)
            atomicAdd(&csum[wc * 64 + n * 16 + lane], colpart[n]);
    }
    __syncthreads();
    if (threadIdx.x < 128)
        invcol[(size_t)bh * NN + jt * 128 + threadIdx.x] = 1.0f / csum[threadIdx.x];
}

// ---------- pass 2: out = (P @ V) / (rowsum + eps), P = exp(sim)*invcol ----------
// grid (8 itiles, 64 bh)
__global__ __launch_bounds__(256, 2) void attn_k(
    const u16* __restrict__ qb, const u16* __restrict__ kb, const u16* __restrict__ vT,
    const float* __restrict__ invcol, u16* __restrict__ ob)
{
    __shared__ char Ks[16384];
    __shared__ char Vs[16384];   // V^T tile [64 dh][128 j], 256B rows
    __shared__ char Ps[32768];   // P tile [128 i][128 j] bf16, 256B rows
    __shared__ float rsum[128];
    const int lane = threadIdx.x & 63;
    const int wid  = threadIdx.x >> 6;
    const int wr = wid >> 1, wc = wid & 1;
    const int it = blockIdx.x;
    const int bh = blockIdx.y;
    const int b = bh >> 3, h = bh & 7;
    if (threadIdx.x < 128) rsum[threadIdx.x] = 0.0f;

    // Q fragments in registers for the whole block
    short8 qf[4][2];
#pragma unroll
    for (int m = 0; m < 4; ++m) {
#pragma unroll
        for (int kk = 0; kk < 2; ++kk) {
            const int i = it * 128 + wr * 64 + m * 16 + (lane & 15);
            qf[m][kk] = *(const short8*)(qb + (size_t)(b * NN + i) * DD + h * DH + kk * 32 + ((lane >> 4) << 3));
        }
    }
    f32x4 oacc[4][2] = {};
    float rs[4][4] = {};
    for (int jt = 0; jt < 8; ++jt) {
        __syncthreads();
        stage128x64(kb + (size_t)(b * NN + jt * 128) * DD + h * DH, DD, Ks, wid, lane);
        stage64x128(vT + (size_t)(h * DH) * 8192 + b * NN + jt * 128, 8192, Vs, wid, lane);
        __syncthreads();
        // sim tile
        f32x4 acc[4][4] = {};
#pragma unroll
        for (int kk = 0; kk < 2; ++kk) {
            const int cb = kk * 64 + (lane >> 4) * 16;
            short8 bk[4];
#pragma unroll
            for (int n = 0; n < 4; ++n) bk[n] = lds_ld128(Ks, wc * 64 + n * 16 + (lane & 15), cb);
#pragma unroll
            for (int m = 0; m < 4; ++m) {
#pragma unroll
                for (int n = 0; n < 4; ++n)
                    acc[m][n] = __builtin_amdgcn_mfma_f32_16x16x32_bf16(qf[m][kk], bk[n], acc[m][n], 0, 0, 0);
            }
        }
        // p = exp(sim)*invcol; accumulate rowsum; write P to LDS (swizzled)
#pragma unroll
        for (int n = 0; n < 4; ++n) {
            const float icv = invcol[(size_t)bh * NN + jt * 128 + wc * 64 + n * 16 + (lane & 15)];
#pragma unroll
            for (int m = 0; m < 4; ++m) {
                const int prow  = wr * 64 + m * 16 + ((lane >> 4) << 2);
                const int pcolb = (wc * 64 + n * 16 + (lane & 15)) * 2;
#pragma unroll
                for (int g = 0; g < 4; ++g) {
                    const float p = __expf(acc[m][n][g] * ATT_SCALE) * icv;
                    rs[m][g] += p;
                    *(u16*)(Ps + ((((prow + g) * 256 + pcolb)) ^ (((prow + g) & 7) << 4))) = f2bf(p);
                }
            }
        }
        __syncthreads();
        // PV: A = P rows (wr half), B = V^T rows (dh) wc half; K = 128 j
#pragma unroll
        for (int kk = 0; kk < 4; ++kk) {
            const int cb = kk * 64 + (lane >> 4) * 16;
            short8 ap[4], bv[2];
#pragma unroll
            for (int m = 0; m < 4; ++m) ap[m] = lds_ld256(Ps, wr * 64 + m * 16 + (lane & 15), cb);
#pragma unroll
            for (int n = 0; n < 2; ++n) bv[n] = lds_ld256(Vs, wc * 32 + n * 16 + (lane & 15), cb);
#pragma unroll
            for (int m = 0; m < 4; ++m) {
#pragma unroll
                for (int n = 0; n < 2; ++n)
                    oacc[m][n] = __builtin_amdgcn_mfma_f32_16x16x32_bf16(ap[m], bv[n], oacc[m][n], 0, 0, 0);
            }
        }
    }
    // reduce rowsum across the 16 column-lanes, then across wc waves via LDS
#pragma unroll
    for (int m = 0; m < 4; ++m) {
#pragma unroll
        for (int g = 0; g < 4; ++g) {
            rs[m][g] += __shfl_xor(rs[m][g], 1);
            rs[m][g] += __shfl_xor(rs[m][g], 2);
            rs[m][g] += __shfl_xor(rs[m][g], 4);
            rs[m][g] += __shfl_xor(rs[m][g], 8);
        }
    }
    if ((lane & 15) == 0) {
#pragma unroll
        for (int m = 0; m < 4; ++m) {
#pragma unroll
            for (int g = 0; g < 4; ++g)
                atomicAdd(&rsum[wr * 64 + m * 16 + ((lane >> 4) << 2) + g], rs[m][g]);
        }
    }
    __syncthreads();
#pragma unroll
    for (int m = 0; m < 4; ++m) {
#pragma unroll
        for (int n = 0; n < 2; ++n) {
            const int row  = wr * 64 + m * 16 + ((lane >> 4) << 2);
            const int dcol = wc * 32 + n * 16 + (lane & 15);
#pragma unroll
            for (int g = 0; g < 4; ++g) {
                const float o = oacc[m][n][g] / (rsum[row + g] + 1e-7f);
                ob[(size_t)(b * NN + it * 128 + row + g) * DD + h * DH + dcol] = f2bf(o);
            }
        }
    }
}

// ---------- launcher ----------

extern "C" void kernel_launch(void* const* d_in, const int* in_sizes, int n_in,
                              void* d_out, int out_size, void* d_ws, size_t ws_size,
                              hipStream_t stream)
{
    (void)in_sizes; (void)n_in; (void)out_size; (void)ws_size;
    const float* x   = (const float*)d_in[0];
    const float* ctx = (const float*)d_in[1];
    const float* Wq  = (const float*)d_in[2];
    const float* Wk  = (const float*)d_in[3];
    const float* Wv  = (const float*)d_in[4];
    const float* Wo  = (const float*)d_in[5];
    const float* bo  = (const float*)d_in[6];
    float* out = (float*)d_out;

    char* w = (char*)d_ws;
    const size_t SZBIG = 8192ull * 512 * 2;            // 8 MiB bf16 buffer
    u16* xb  = (u16*)(w);                              // x bf16, later reused as ob
    u16* cb  = (u16*)(w + SZBIG);
    u16* qb  = (u16*)(w + 2 * SZBIG);
    u16* kb  = (u16*)(w + 3 * SZBIG);
    u16* vT  = (u16*)(w + 4 * SZBIG);                  // [512][8192]
    u16* wqb = (u16*)(w + 5 * SZBIG);
    u16* wkb = (u16*)(w + 5 * SZBIG + 524288);
    u16* wvb = (u16*)(w + 5 * SZBIG + 2 * 524288);
    u16* wob = (u16*)(w + 5 * SZBIG + 3 * 524288);
    float* invcol = (float*)(w + 5 * SZBIG + 4 * 524288);
    u16* ob = xb;                                      // reuse (x dead after q GEMM)

    f2bf_k<<<4096, 256, 0, stream>>>(x,   xb,  1048576);
    f2bf_k<<<4096, 256, 0, stream>>>(ctx, cb,  1048576);
    f2bf_k<<<256,  256, 0, stream>>>(Wq,  wqb, 65536);
    f2bf_k<<<256,  256, 0, stream>>>(Wk,  wkb, 65536);
    f2bf_k<<<256,  256, 0, stream>>>(Wv,  wvb, 65536);
    f2bf_k<<<256,  256, 0, stream>>>(Wo,  wob, 65536);

    dim3 gg(4, 64);
    gemm_bt<0><<<gg, 256, 0, stream>>>(xb, wqb, qb, nullptr);
    gemm_bt<0><<<gg, 256, 0, stream>>>(cb, wkb, kb, nullptr);
    gemm_bt<1><<<gg, 256, 0, stream>>>(cb, wvb, vT, nullptr);

    colsum_k<<<dim3(8, 64), 256, 0, stream>>>(qb, kb, invcol);
    attn_k  <<<dim3(8, 64), 256, 0, stream>>>(qb, kb, vT, invcol, ob);

    gemm_bt<2><<<gg, 256, 0, stream>>>(ob, wob, out, bo);
}

// Round 3
// 171.361 us; speedup vs baseline: 1.3445x; 1.3445x over previous
//
#include <hip/hip_runtime.h>

typedef __attribute__((ext_vector_type(8))) short short8;
typedef __attribute__((ext_vector_type(4))) float f32x4;
typedef __attribute__((ext_vector_type(16))) float f32x16;
typedef __attribute__((ext_vector_type(4))) unsigned short ushort4v;
typedef __attribute__((ext_vector_type(4))) unsigned int u32x4;
typedef unsigned short u16;
typedef unsigned int u32;

#define NN 1024
#define DD 512
#define DH 64
#define ATT_SCALE 0.125f

// ---------- helpers ----------

__device__ __forceinline__ u16 f2bf(float f) {
    unsigned u = __float_as_uint(f);
    u += 0x7fffu + ((u >> 16) & 1u);   // RNE
    return (u16)(u >> 16);
}

// swizzled LDS reads: physical = (row*LD + colbyte) ^ ((row&7)<<4)
__device__ __forceinline__ short8 lds_ld128(const char* base, int row, int colbyte) {
    int off = (row * 128 + colbyte) ^ ((row & 7) << 4);
    return *(const short8*)(base + off);
}

// stage 128 rows x 64 cols bf16 (16KB) tile; global row-major, ldRow elements.
__device__ __forceinline__ void stage128x64(const u16* g, int ldRow, char* lds,
                                            int wid, int lane) {
#pragma unroll
    for (int r = 0; r < 4; ++r) {
        int cidx = (r * 4 + wid) * 64 + lane;        // 16B chunk index, 1024 total
        int row  = cidx >> 3;                        // 8 chunks per 128B row
        int ch   = (cidx & 7) ^ (row & 7);           // inverse-swizzled source chunk
        const char* src = (const char*)(g + row * ldRow) + ch * 16;
        __builtin_amdgcn_global_load_lds(
            (const __attribute__((address_space(1))) unsigned int*)src,
            (__attribute__((address_space(3))) unsigned int*)(lds + (r * 4 + wid) * 1024),
            16, 0, 0);
    }
}

// ---------- fused fp32 -> bf16 convert for all 6 tensors ----------
// regions (in float4 units): x 1048576 | ctx 1048576 | Wq,Wk,Wv,Wo 65536 each
__global__ void f2bf_all(const float* __restrict__ x, const float* __restrict__ ctx,
                         const float* __restrict__ Wq, const float* __restrict__ Wk,
                         const float* __restrict__ Wv, const float* __restrict__ Wo,
                         u16* __restrict__ xb, u16* __restrict__ cb,
                         u16* __restrict__ wb /* 4 weights contiguous */) {
    int i = blockIdx.x * blockDim.x + threadIdx.x;   // float4 index, 2359296 total
    const float* src;
    u16* dst;
    int off;
    if (i < 1048576)      { src = x;   dst = xb; off = i; }
    else if (i < 2097152) { src = ctx; dst = cb; off = i - 1048576; }
    else {
        int wi = i - 2097152;           // 0..262143
        int which = wi >> 16;           // /65536
        off = wi & 65535;
        dst = wb + (size_t)which * 262144;
        src = (which == 0) ? Wq : (which == 1) ? Wk : (which == 2) ? Wv : Wo;
    }
    float4 v = ((const float4*)src)[off];
    ushort4v o;
    o.x = f2bf(v.x); o.y = f2bf(v.y); o.z = f2bf(v.z); o.w = f2bf(v.w);
    *(ushort4v*)(dst + (size_t)off * 4) = o;
}

// ---------- GEMM: C[M,512] = A[M,512] @ B[512,512]^T ----------
// MODE 0: bf16 row-major out   MODE 1: bf16 transposed out [512][8192]
// MODE 2: fp32 out + bias
template <int MODE>
__global__ __launch_bounds__(256, 2) void gemm_bt(
    const u16* __restrict__ A, const u16* __restrict__ B,
    void* __restrict__ Out, const float* __restrict__ bias)
{
    __shared__ char As[16384];
    __shared__ char Bs[16384];
    const int lane = threadIdx.x & 63;
    const int wid  = threadIdx.x >> 6;
    const int wr = wid >> 1, wc = wid & 1;
    const int rowBase = blockIdx.y * 128;
    const int colBase = blockIdx.x * 128;

    f32x4 acc[4][4] = {};
    for (int kt = 0; kt < 8; ++kt) {
        __syncthreads();
        stage128x64(A + (size_t)rowBase * DD + kt * 64, DD, As, wid, lane);
        stage128x64(B + (size_t)colBase * DD + kt * 64, DD, Bs, wid, lane);
        __syncthreads();
#pragma unroll
        for (int kk = 0; kk < 2; ++kk) {
            const int cb = kk * 64 + (lane >> 4) * 16;
            short8 af[4], bf[4];
#pragma unroll
            for (int m = 0; m < 4; ++m) af[m] = lds_ld128(As, wr * 64 + m * 16 + (lane & 15), cb);
#pragma unroll
            for (int n = 0; n < 4; ++n) bf[n] = lds_ld128(Bs, wc * 64 + n * 16 + (lane & 15), cb);
#pragma unroll
            for (int m = 0; m < 4; ++m) {
#pragma unroll
                for (int n = 0; n < 4; ++n)
                    acc[m][n] = __builtin_amdgcn_mfma_f32_16x16x32_bf16(af[m], bf[n], acc[m][n], 0, 0, 0);
            }
        }
    }
#pragma unroll
    for (int m = 0; m < 4; ++m) {
#pragma unroll
        for (int n = 0; n < 4; ++n) {
            const int r0 = rowBase + wr * 64 + m * 16 + ((lane >> 4) << 2);
            const int c  = colBase + wc * 64 + n * 16 + (lane & 15);
            if (MODE == 0) {
                u16* O = (u16*)Out;
#pragma unroll
                for (int g = 0; g < 4; ++g) O[(size_t)(r0 + g) * DD + c] = f2bf(acc[m][n][g]);
            } else if (MODE == 1) {
                u16* O = (u16*)Out;      // [512][8192]
                ushort4v pk;
#pragma unroll
                for (int g = 0; g < 4; ++g) pk[g] = f2bf(acc[m][n][g]);
                *(ushort4v*)(O + (size_t)c * 8192 + r0) = pk;
            } else {
                float* O = (float*)Out;
                const float bb = bias[c];
#pragma unroll
                for (int g = 0; g < 4; ++g) O[(size_t)(r0 + g) * DD + c] = acc[m][n][g] + bb;
            }
        }
    }
}

// ---------- pass 1: inv column-sum of exp(sim) ----------
// One wave per (bh, 32-j band); loops all 1024 i. No LDS, no atomics.
// S^T[j][i] = mfma_32x32x16(A=K rows j, B=Q^T)  (C: col=i=lane&31, row j per reg)
__global__ void colsum_k(const u16* __restrict__ qb, const u16* __restrict__ kb,
                         float* __restrict__ invcol)
{
    const int lane = threadIdx.x & 63;
    const int wid  = threadIdx.x >> 6;
    const int il = lane & 31, hh = lane >> 5;
    const int jbase = (blockIdx.x * 4 + wid) * 32;
    const int bh = blockIdx.y;
    const int b = bh >> 3, h = bh & 7;

    const u16* kRow = kb + (size_t)(b * NN + jbase + il) * DD + h * DH + hh * 8;
    short8 kf[4];
#pragma unroll
    for (int t = 0; t < 4; ++t) kf[t] = *(const short8*)(kRow + t * 16);

    float cp[16] = {};
    for (int it = 0; it < 32; ++it) {
        const u16* qRow = qb + (size_t)(b * NN + it * 32 + il) * DD + h * DH + hh * 8;
        short8 qf[4];
#pragma unroll
        for (int t = 0; t < 4; ++t) qf[t] = *(const short8*)(qRow + t * 16);
        f32x16 sa = {};
#pragma unroll
        for (int t = 0; t < 4; ++t)
            sa = __builtin_amdgcn_mfma_f32_32x32x16_bf16(kf[t], qf[t], sa, 0, 0, 0);
#pragma unroll
        for (int r = 0; r < 16; ++r) cp[r] += __expf(sa[r] * ATT_SCALE);
    }
    // reduce across the 32 i-lanes within each half (j sets differ between halves)
#pragma unroll
    for (int r = 0; r < 16; ++r) {
        cp[r] += __shfl_xor(cp[r], 1);
        cp[r] += __shfl_xor(cp[r], 2);
        cp[r] += __shfl_xor(cp[r], 4);
        cp[r] += __shfl_xor(cp[r], 8);
        cp[r] += __shfl_xor(cp[r], 16);
    }
    if (il == 0) {
#pragma unroll
        for (int r = 0; r < 16; ++r) {
            const int j = jbase + (r & 3) + 8 * (r >> 2) + 4 * hh;
            invcol[(size_t)bh * NN + j] = 1.0f / cp[r];
        }
    }
}

// ---------- pass 2: out^T = V^T @ P^T, P = exp(sim)*invcol; divide by rowsum ----------
// One wave per (bh, 32-i band). No LDS, no barriers. P stays in registers.
__global__ void attn_k(const u16* __restrict__ qb, const u16* __restrict__ kb,
                       const u16* __restrict__ vT, const float* __restrict__ invcol,
                       u16* __restrict__ ob)
{
    const int lane = threadIdx.x & 63;
    const int wid  = threadIdx.x >> 6;
    const int il = lane & 31, hh = lane >> 5;
    const int ibase = (blockIdx.x * 4 + wid) * 32;
    const int bh = blockIdx.y;
    const int b = bh >> 3, h = bh & 7;

    const u16* qRow = qb + (size_t)(b * NN + ibase + il) * DD + h * DH + hh * 8;
    short8 qf[4];
#pragma unroll
    for (int t = 0; t < 4; ++t) qf[t] = *(const short8*)(qRow + t * 16);

    f32x16 oacc[2] = {};
    float rs = 0.0f;

    for (int jt = 0; jt < 32; ++jt) {
        const int jb = jt * 32;
        const u16* kRow = kb + (size_t)(b * NN + jb + il) * DD + h * DH + hh * 8;
        short8 kf[4];
#pragma unroll
        for (int t = 0; t < 4; ++t) kf[t] = *(const short8*)(kRow + t * 16);
        // V^T fragments: A[dh row = l&31][k=j], contiguous in j
        const u16* vRow0 = vT + (size_t)(h * DH + il) * 8192 + b * NN + jb + hh * 8;
        short8 vf[2][2];
#pragma unroll
        for (int tc = 0; tc < 2; ++tc) {
            vf[0][tc] = *(const short8*)(vRow0 + tc * 16);
            vf[1][tc] = *(const short8*)(vRow0 + 32 * 8192 + tc * 16);
        }
        // S^T tile
        f32x16 sa = {};
#pragma unroll
        for (int t = 0; t < 4; ++t)
            sa = __builtin_amdgcn_mfma_f32_32x32x16_bf16(kf[t], qf[t], sa, 0, 0, 0);
        // P = exp(S)*invcol; pack to bf16 pairs (j-consecutive within s-group)
        u32 pk[4][2];
#pragma unroll
        for (int s = 0; s < 4; ++s) {
            const float4 ic = *(const float4*)(invcol + (size_t)bh * NN + jb + 8 * s + 4 * hh);
            const float p0 = __expf(sa[4 * s + 0] * ATT_SCALE) * ic.x;
            const float p1 = __expf(sa[4 * s + 1] * ATT_SCALE) * ic.y;
            const float p2 = __expf(sa[4 * s + 2] * ATT_SCALE) * ic.z;
            const float p3 = __expf(sa[4 * s + 3] * ATT_SCALE) * ic.w;
            rs += (p0 + p1) + (p2 + p3);
            pk[s][0] = (u32)f2bf(p0) | ((u32)f2bf(p1) << 16);
            pk[s][1] = (u32)f2bf(p2) | ((u32)f2bf(p3) << 16);
        }
        // build P^T B-fragments (half-wave exchange) and do PV
#pragma unroll
        for (int tc = 0; tc < 2; ++tc) {
            const u32 snd0 = hh ? pk[2 * tc][0] : pk[2 * tc + 1][0];
            const u32 snd1 = hh ? pk[2 * tc][1] : pk[2 * tc + 1][1];
            const u32 rcv0 = (u32)__shfl_xor((int)snd0, 32);
            const u32 rcv1 = (u32)__shfl_xor((int)snd1, 32);
            u32x4 pw;
            pw.x = hh ? rcv0 : pk[2 * tc][0];
            pw.y = hh ? rcv1 : pk[2 * tc][1];
            pw.z = hh ? pk[2 * tc + 1][0] : rcv0;
            pw.w = hh ? pk[2 * tc + 1][1] : rcv1;
            const short8 pf = __builtin_bit_cast(short8, pw);
#pragma unroll
            for (int n = 0; n < 2; ++n)
                oacc[n] = __builtin_amdgcn_mfma_f32_32x32x16_bf16(vf[n][tc], pf, oacc[n], 0, 0, 0);
        }
    }
    rs += __shfl_xor(rs, 32);
    const float inv = 1.0f / (rs + 1e-7f);
    u16* oRow = ob + (size_t)(b * NN + ibase + il) * DD + h * DH;
#pragma unroll
    for (int n = 0; n < 2; ++n) {
#pragma unroll
        for (int s = 0; s < 4; ++s) {
            ushort4v st;
#pragma unroll
            for (int g = 0; g < 4; ++g) st[g] = f2bf(oacc[n][4 * s + g] * inv);
            *(ushort4v*)(oRow + n * 32 + 8 * s + 4 * hh) = st;
        }
    }
}

// ---------- launcher ----------

extern "C" void kernel_launch(void* const* d_in, const int* in_sizes, int n_in,
                              void* d_out, int out_size, void* d_ws, size_t ws_size,
                              hipStream_t stream)
{
    (void)in_sizes; (void)n_in; (void)out_size; (void)ws_size;
    const float* x   = (const float*)d_in[0];
    const float* ctx = (const float*)d_in[1];
    const float* Wq  = (const float*)d_in[2];
    const float* Wk  = (const float*)d_in[3];
    const float* Wv  = (const float*)d_in[4];
    const float* Wo  = (const float*)d_in[5];
    const float* bo  = (const float*)d_in[6];
    float* out = (float*)d_out;

    char* w = (char*)d_ws;
    const size_t SZBIG = 8192ull * 512 * 2;            // 8 MiB bf16 buffer
    u16* xb  = (u16*)(w);                              // x bf16, later reused as ob
    u16* cb  = (u16*)(w + SZBIG);
    u16* qb  = (u16*)(w + 2 * SZBIG);
    u16* kb  = (u16*)(w + 3 * SZBIG);
    u16* vT  = (u16*)(w + 4 * SZBIG);                  // [512][8192]
    u16* wb  = (u16*)(w + 5 * SZBIG);                  // wq,wk,wv,wo contiguous
    u16* wqb = wb;
    u16* wkb = wb + 262144;
    u16* wvb = wb + 2 * 262144;
    u16* wob = wb + 3 * 262144;
    float* invcol = (float*)(w + 5 * SZBIG + 4 * 524288);
    u16* ob = xb;                                      // reuse (x dead after q GEMM)

    f2bf_all<<<9216, 256, 0, stream>>>(x, ctx, Wq, Wk, Wv, Wo, xb, cb, wb);

    dim3 gg(4, 64);
    gemm_bt<0><<<gg, 256, 0, stream>>>(xb, wqb, qb, nullptr);
    gemm_bt<0><<<gg, 256, 0, stream>>>(cb, wkb, kb, nullptr);
    gemm_bt<1><<<gg, 256, 0, stream>>>(cb, wvb, vT, nullptr);

    colsum_k<<<dim3(8, 64), 256, 0, stream>>>(qb, kb, invcol);
    attn_k  <<<dim3(8, 64), 256, 0, stream>>>(qb, kb, vT, invcol, ob);

    gemm_bt<2><<<gg, 256, 0, stream>>>(ob, wob, out, bo);
}

// Round 4
// 168.383 us; speedup vs baseline: 1.3683x; 1.0177x over previous
//
#include <hip/hip_runtime.h>

typedef __attribute__((ext_vector_type(8))) short short8;
typedef __attribute__((ext_vector_type(4))) float f32x4;
typedef __attribute__((ext_vector_type(16))) float f32x16;
typedef __attribute__((ext_vector_type(4))) unsigned short ushort4v;
typedef __attribute__((ext_vector_type(4))) unsigned int u32x4;
typedef unsigned short u16;
typedef unsigned int u32;

#define NN 1024
#define DD 512
#define DH 64
#define ATT_SCALE 0.125f
#define EXP2C 0.18033688f   /* ATT_SCALE * log2(e) */

// ---------- helpers ----------

__device__ __forceinline__ u16 f2bf(float f) {
    unsigned u = __float_as_uint(f);
    u += 0x7fffu + ((u >> 16) & 1u);   // RNE
    return (u16)(u >> 16);
}

__device__ __forceinline__ short8 lds_ld128(const char* base, int row, int colbyte) {
    int off = (row * 128 + colbyte) ^ ((row & 7) << 4);
    return *(const short8*)(base + off);
}

__device__ __forceinline__ void stage128x64(const u16* g, int ldRow, char* lds,
                                            int wid, int lane) {
#pragma unroll
    for (int r = 0; r < 4; ++r) {
        int cidx = (r * 4 + wid) * 64 + lane;
        int row  = cidx >> 3;
        int ch   = (cidx & 7) ^ (row & 7);
        const char* src = (const char*)(g + row * ldRow) + ch * 16;
        __builtin_amdgcn_global_load_lds(
            (const __attribute__((address_space(1))) unsigned int*)src,
            (__attribute__((address_space(3))) unsigned int*)(lds + (r * 4 + wid) * 1024),
            16, 0, 0);
    }
}

// ---------- fused fp32 -> bf16 convert ----------
__global__ void f2bf_all(const float* __restrict__ x, const float* __restrict__ ctx,
                         const float* __restrict__ Wq, const float* __restrict__ Wk,
                         const float* __restrict__ Wv, const float* __restrict__ Wo,
                         u16* __restrict__ xb, u16* __restrict__ cb,
                         u16* __restrict__ wb) {
    int i = blockIdx.x * blockDim.x + threadIdx.x;   // float4 index, 2359296 total
    const float* src;
    u16* dst;
    int off;
    if (i < 1048576)      { src = x;   dst = xb; off = i; }
    else if (i < 2097152) { src = ctx; dst = cb; off = i - 1048576; }
    else {
        int wi = i - 2097152;
        int which = wi >> 16;
        off = wi & 65535;
        dst = wb + (size_t)which * 262144;
        src = (which == 0) ? Wq : (which == 1) ? Wk : (which == 2) ? Wv : Wo;
    }
    float4 v = ((const float4*)src)[off];
    ushort4v o;
    o.x = f2bf(v.x); o.y = f2bf(v.y); o.z = f2bf(v.z); o.w = f2bf(v.w);
    *(ushort4v*)(dst + (size_t)off * 4) = o;
}

// ---------- GEMM: C[M,512] = A[M,512] @ B[512,512]^T ----------
template <int MODE>
__global__ __launch_bounds__(256, 2) void gemm_bt(
    const u16* __restrict__ A, const u16* __restrict__ B,
    void* __restrict__ Out, const float* __restrict__ bias)
{
    __shared__ char As[16384];
    __shared__ char Bs[16384];
    const int lane = threadIdx.x & 63;
    const int wid  = threadIdx.x >> 6;
    const int wr = wid >> 1, wc = wid & 1;
    // XCD-bijective swizzle: 256 blocks = 8 XCDs x 32
    const int n = blockIdx.x + 4 * blockIdx.y;
    const int L = (n & 7) * 32 + (n >> 3);
    const int rowBase = (L >> 2) * 128;
    const int colBase = (L & 3) * 128;

    f32x4 acc[4][4] = {};
    for (int kt = 0; kt < 8; ++kt) {
        __syncthreads();
        stage128x64(A + (size_t)rowBase * DD + kt * 64, DD, As, wid, lane);
        stage128x64(B + (size_t)colBase * DD + kt * 64, DD, Bs, wid, lane);
        __syncthreads();
#pragma unroll
        for (int kk = 0; kk < 2; ++kk) {
            const int cb = kk * 64 + (lane >> 4) * 16;
            short8 af[4], bf[4];
#pragma unroll
            for (int m = 0; m < 4; ++m) af[m] = lds_ld128(As, wr * 64 + m * 16 + (lane & 15), cb);
#pragma unroll
            for (int nn2 = 0; nn2 < 4; ++nn2) bf[nn2] = lds_ld128(Bs, wc * 64 + nn2 * 16 + (lane & 15), cb);
#pragma unroll
            for (int m = 0; m < 4; ++m) {
#pragma unroll
                for (int nn2 = 0; nn2 < 4; ++nn2)
                    acc[m][nn2] = __builtin_amdgcn_mfma_f32_16x16x32_bf16(af[m], bf[nn2], acc[m][nn2], 0, 0, 0);
            }
        }
    }
#pragma unroll
    for (int m = 0; m < 4; ++m) {
#pragma unroll
        for (int nn2 = 0; nn2 < 4; ++nn2) {
            const int r0 = rowBase + wr * 64 + m * 16 + ((lane >> 4) << 2);
            const int c  = colBase + wc * 64 + nn2 * 16 + (lane & 15);
            if (MODE == 0) {
                u16* O = (u16*)Out;
#pragma unroll
                for (int g = 0; g < 4; ++g) O[(size_t)(r0 + g) * DD + c] = f2bf(acc[m][nn2][g]);
            } else if (MODE == 1) {
                u16* O = (u16*)Out;      // [512][8192]
                ushort4v pk;
#pragma unroll
                for (int g = 0; g < 4; ++g) pk[g] = f2bf(acc[m][nn2][g]);
                *(ushort4v*)(O + (size_t)c * 8192 + r0) = pk;
            } else {
                float* O = (float*)Out;
                const float bb = bias[c];
#pragma unroll
                for (int g = 0; g < 4; ++g) O[(size_t)(r0 + g) * DD + c] = acc[m][nn2][g] + bb;
            }
        }
    }
}

// ---------- pass 1: inv column-sum of exp(sim) ----------
// grid (16,64); block = 2 j-bands x 2 i-halves (4 waves).
__global__ __launch_bounds__(256, 4) void colsum_k(
    const u16* __restrict__ qb, const u16* __restrict__ kb, float* __restrict__ invcol)
{
    __shared__ float csum[64];
    const int lane = threadIdx.x & 63;
    const int wid  = threadIdx.x >> 6;
    const int il = lane & 31, hh = lane >> 5;
    const int n = blockIdx.x + 16 * blockIdx.y;
    const int L = (n & 7) * 128 + (n >> 3);
    const int xt = L & 15;
    const int bh = L >> 4;
    const int b = bh >> 3, h = bh & 7;
    const int jbp = wid & 1;          // band within pair
    const int ih  = wid >> 1;         // i half
    const int jbase = (xt * 2 + jbp) * 32;

    if (threadIdx.x < 64) csum[threadIdx.x] = 0.0f;
    __syncthreads();

    const u16* kRow = kb + (size_t)(b * NN + jbase + il) * DD + h * DH + hh * 8;
    short8 kf[4];
#pragma unroll
    for (int t = 0; t < 4; ++t) kf[t] = *(const short8*)(kRow + t * 16);

    const u16* qbase = qb + (size_t)(b * NN + il) * DD + h * DH + hh * 8;
    auto loadq = [&](short8 (&qf)[4], int it) {
        const u16* qRow = qbase + (size_t)(it * 32) * DD;
#pragma unroll
        for (int t = 0; t < 4; ++t) qf[t] = *(const short8*)(qRow + t * 16);
    };
    float cp[16] = {};
    auto body = [&](const short8 (&qf)[4]) {
        f32x16 sa = {};
#pragma unroll
        for (int t = 0; t < 4; ++t)
            sa = __builtin_amdgcn_mfma_f32_32x32x16_bf16(kf[t], qf[t], sa, 0, 0, 0);
#pragma unroll
        for (int r = 0; r < 16; ++r) cp[r] += exp2f(sa[r] * EXP2C);
    };

    const int it0 = ih * 16;
    short8 qA[4], qB[4];
    loadq(qA, it0);
    for (int u = 0; u < 16; u += 2) {
        loadq(qB, it0 + u + 1);
        body(qA);
        loadq(qA, it0 + ((u + 2) & 15));
        body(qB);
    }
#pragma unroll
    for (int r = 0; r < 16; ++r) {
        cp[r] += __shfl_xor(cp[r], 1);
        cp[r] += __shfl_xor(cp[r], 2);
        cp[r] += __shfl_xor(cp[r], 4);
        cp[r] += __shfl_xor(cp[r], 8);
        cp[r] += __shfl_xor(cp[r], 16);
    }
    if (il == 0) {
#pragma unroll
        for (int r = 0; r < 16; ++r)
            atomicAdd(&csum[jbp * 32 + (r & 3) + 8 * (r >> 2) + 4 * hh], cp[r]);
    }
    __syncthreads();
    if (threadIdx.x < 64)
        invcol[(size_t)bh * NN + xt * 64 + threadIdx.x] = 1.0f / csum[threadIdx.x];
}

// ---------- pass 2: out^T = V^T @ P^T ----------
// grid (16,64); block = 2 i-bands x 2 j-halves (4 waves), LDS partial combine.
__global__ __launch_bounds__(256, 4) void attn_k(
    const u16* __restrict__ qb, const u16* __restrict__ kb, const u16* __restrict__ vT,
    const float* __restrict__ invcol, u16* __restrict__ ob)
{
    __shared__ float cmbO[2][32][64];
    __shared__ float cmbR[2][64];
    const int lane = threadIdx.x & 63;
    const int wid  = threadIdx.x >> 6;
    const int il = lane & 31, hh = lane >> 5;
    const int n = blockIdx.x + 16 * blockIdx.y;
    const int L = (n & 7) * 128 + (n >> 3);
    const int xt = L & 15;
    const int bh = L >> 4;
    const int b = bh >> 3, h = bh & 7;
    const int ibp = wid & 1;          // i band within pair
    const int jh  = wid >> 1;         // j half
    const int ibase = (xt * 2 + ibp) * 32;

    const u16* qRow = qb + (size_t)(b * NN + ibase + il) * DD + h * DH + hh * 8;
    short8 qf[4];
#pragma unroll
    for (int t = 0; t < 4; ++t) qf[t] = *(const short8*)(qRow + t * 16);

    const u16* kbase = kb + (size_t)(b * NN + il) * DD + h * DH + hh * 8;
    const u16* vbase = vT + (size_t)(h * DH + il) * 8192 + b * NN + hh * 8;
    const float* icbase = invcol + (size_t)bh * NN + 4 * hh;

    f32x16 oacc[2] = {};
    float rs = 0.0f;

    auto loadk = [&](short8 (&kf)[4], int jt) {
        const u16* kRow = kbase + (size_t)(jt * 32) * DD;
#pragma unroll
        for (int t = 0; t < 4; ++t) kf[t] = *(const short8*)(kRow + t * 16);
    };
    auto body = [&](const short8 (&kf)[4], int jt) {
        const int jb = jt * 32;
        const u16* vRow0 = vbase + jb;
        short8 vf[2][2];
#pragma unroll
        for (int tc = 0; tc < 2; ++tc) {
            vf[0][tc] = *(const short8*)(vRow0 + tc * 16);
            vf[1][tc] = *(const short8*)(vRow0 + 32 * 8192 + tc * 16);
        }
        f32x16 sa = {};
#pragma unroll
        for (int t = 0; t < 4; ++t)
            sa = __builtin_amdgcn_mfma_f32_32x32x16_bf16(kf[t], qf[t], sa, 0, 0, 0);
        u32 pk[4][2];
#pragma unroll
        for (int s = 0; s < 4; ++s) {
            const float4 ic = *(const float4*)(icbase + jb + 8 * s);
            const float p0 = exp2f(sa[4 * s + 0] * EXP2C) * ic.x;
            const float p1 = exp2f(sa[4 * s + 1] * EXP2C) * ic.y;
            const float p2 = exp2f(sa[4 * s + 2] * EXP2C) * ic.z;
            const float p3 = exp2f(sa[4 * s + 3] * EXP2C) * ic.w;
            rs += (p0 + p1) + (p2 + p3);
            pk[s][0] = (u32)f2bf(p0) | ((u32)f2bf(p1) << 16);
            pk[s][1] = (u32)f2bf(p2) | ((u32)f2bf(p3) << 16);
        }
#pragma unroll
        for (int tc = 0; tc < 2; ++tc) {
            const u32 snd0 = hh ? pk[2 * tc][0] : pk[2 * tc + 1][0];
            const u32 snd1 = hh ? pk[2 * tc][1] : pk[2 * tc + 1][1];
            const u32 rcv0 = (u32)__shfl_xor((int)snd0, 32);
            const u32 rcv1 = (u32)__shfl_xor((int)snd1, 32);
            u32x4 pw;
            pw.x = hh ? rcv0 : pk[2 * tc][0];
            pw.y = hh ? rcv1 : pk[2 * tc][1];
            pw.z = hh ? pk[2 * tc + 1][0] : rcv0;
            pw.w = hh ? pk[2 * tc + 1][1] : rcv1;
            const short8 pf = __builtin_bit_cast(short8, pw);
#pragma unroll
            for (int m = 0; m < 2; ++m)
                oacc[m] = __builtin_amdgcn_mfma_f32_32x32x16_bf16(vf[m][tc], pf, oacc[m], 0, 0, 0);
        }
    };

    const int jt0 = jh * 16;
    short8 kA[4], kB[4];
    loadk(kA, jt0);
    for (int u = 0; u < 16; u += 2) {
        loadk(kB, jt0 + u + 1);
        body(kA, jt0 + u);
        loadk(kA, jt0 + ((u + 2) & 15));
        body(kB, jt0 + u + 1);
    }

    rs += __shfl_xor(rs, 32);
    if (jh == 1) {
#pragma unroll
        for (int m = 0; m < 2; ++m)
#pragma unroll
            for (int r = 0; r < 16; ++r) cmbO[ibp][m * 16 + r][lane] = oacc[m][r];
        cmbR[ibp][lane] = rs;
    }
    __syncthreads();
    if (jh == 0) {
#pragma unroll
        for (int m = 0; m < 2; ++m)
#pragma unroll
            for (int r = 0; r < 16; ++r) oacc[m][r] += cmbO[ibp][m * 16 + r][lane];
        rs += cmbR[ibp][lane];
        const float inv = 1.0f / (rs + 1e-7f);
        u16* oRow = ob + (size_t)(b * NN + ibase + il) * DD + h * DH;
#pragma unroll
        for (int m = 0; m < 2; ++m) {
#pragma unroll
            for (int s = 0; s < 4; ++s) {
                ushort4v st;
#pragma unroll
                for (int g = 0; g < 4; ++g) st[g] = f2bf(oacc[m][4 * s + g] * inv);
                *(ushort4v*)(oRow + m * 32 + 8 * s + 4 * hh) = st;
            }
        }
    }
}

// ---------- launcher ----------

extern "C" void kernel_launch(void* const* d_in, const int* in_sizes, int n_in,
                              void* d_out, int out_size, void* d_ws, size_t ws_size,
                              hipStream_t stream)
{
    (void)in_sizes; (void)n_in; (void)out_size; (void)ws_size;
    const float* x   = (const float*)d_in[0];
    const float* ctx = (const float*)d_in[1];
    const float* Wq  = (const float*)d_in[2];
    const float* Wk  = (const float*)d_in[3];
    const float* Wv  = (const float*)d_in[4];
    const float* Wo  = (const float*)d_in[5];
    const float* bo  = (const float*)d_in[6];
    float* out = (float*)d_out;

    char* w = (char*)d_ws;
    const size_t SZBIG = 8192ull * 512 * 2;            // 8 MiB bf16 buffer
    u16* xb  = (u16*)(w);
    u16* cb  = (u16*)(w + SZBIG);
    u16* qb  = (u16*)(w + 2 * SZBIG);
    u16* kb  = (u16*)(w + 3 * SZBIG);
    u16* vT  = (u16*)(w + 4 * SZBIG);                  // [512][8192]
    u16* wb  = (u16*)(w + 5 * SZBIG);
    u16* wqb = wb;
    u16* wkb = wb + 262144;
    u16* wvb = wb + 2 * 262144;
    u16* wob = wb + 3 * 262144;
    float* invcol = (float*)(w + 5 * SZBIG + 4 * 524288);
    u16* ob = xb;                                      // reuse (x dead after q GEMM)

    f2bf_all<<<9216, 256, 0, stream>>>(x, ctx, Wq, Wk, Wv, Wo, xb, cb, wb);

    dim3 gg(4, 64);
    gemm_bt<0><<<gg, 256, 0, stream>>>(xb, wqb, qb, nullptr);
    gemm_bt<0><<<gg, 256, 0, stream>>>(cb, wkb, kb, nullptr);
    gemm_bt<1><<<gg, 256, 0, stream>>>(cb, wvb, vT, nullptr);

    colsum_k<<<dim3(16, 64), 256, 0, stream>>>(qb, kb, invcol);
    attn_k  <<<dim3(16, 64), 256, 0, stream>>>(qb, kb, vT, invcol, ob);

    gemm_bt<2><<<gg, 256, 0, stream>>>(ob, wob, out, bo);
}